// Round 1
// baseline (314.498 us; speedup 1.0000x reference)
//
#include <hip/hip_runtime.h>
#include <math.h>

// Problem constants (fixed by the reference).
constexpr int BATCH = 4;
constexpr int SEQ   = 2048;
constexpr int NEMB  = 1024;
constexpr int HS    = 64;

// ---------------------------------------------------------------------------
// Kernel 1: fused QKV projection.
//   q[bt][h] = sum_c x[bt][c] * Wq[h][c]   (likewise k, v)
// GEMM C[8192,64] = X[8192,1024] * W[64,1024]^T, one blockIdx.y per weight.
// BM=64, BN=64(=HS), BK=16; 256 threads; 4x4 register tile per thread.
// ---------------------------------------------------------------------------
__launch_bounds__(256) __global__
void qkv_proj_kernel(const float* __restrict__ x,
                     const float* __restrict__ Wq,
                     const float* __restrict__ Wk,
                     const float* __restrict__ Wv,
                     float* __restrict__ qkv)
{
    const int m0   = blockIdx.x * 64;
    const int wsel = blockIdx.y;
    const float* W = (wsel == 0) ? Wq : (wsel == 1) ? Wk : Wv;
    float* outp = qkv + (size_t)wsel * ((size_t)BATCH * SEQ * HS);

    // [k][m] / [k][n] layout, leading dim padded to 68 (16B-aligned rows, no conflicts)
    __shared__ float Xs[16][68];
    __shared__ float Ws_[16][68];

    const int t  = threadIdx.x;
    const int tx = t & 15;        // n sub-tile (cols tx*4..+3)
    const int ty = t >> 4;        // m sub-tile (rows ty*4..+3)
    const int lm = t >> 2;        // load: row 0..63
    const int lk = (t & 3) * 4;   // load: k offset 0,4,8,12

    float acc[4][4] = {{0.f}};

    for (int k0 = 0; k0 < NEMB; k0 += 16) {
        float4 xa = *(const float4*)(x + (size_t)(m0 + lm) * NEMB + k0 + lk);
        float4 wa = *(const float4*)(W + (size_t)lm * NEMB + k0 + lk);
        Xs[lk + 0][lm] = xa.x;  Xs[lk + 1][lm] = xa.y;
        Xs[lk + 2][lm] = xa.z;  Xs[lk + 3][lm] = xa.w;
        Ws_[lk + 0][lm] = wa.x; Ws_[lk + 1][lm] = wa.y;
        Ws_[lk + 2][lm] = wa.z; Ws_[lk + 3][lm] = wa.w;
        __syncthreads();
#pragma unroll
        for (int kk = 0; kk < 16; ++kk) {
            float4 a4 = *(float4*)&Xs[kk][ty * 4];
            float4 b4 = *(float4*)&Ws_[kk][tx * 4];
            float a[4]  = {a4.x, a4.y, a4.z, a4.w};
            float bb[4] = {b4.x, b4.y, b4.z, b4.w};
#pragma unroll
            for (int i = 0; i < 4; ++i)
#pragma unroll
                for (int j = 0; j < 4; ++j)
                    acc[i][j] += a[i] * bb[j];
        }
        __syncthreads();
    }
#pragma unroll
    for (int i = 0; i < 4; ++i) {
        float4 r = make_float4(acc[i][0], acc[i][1], acc[i][2], acc[i][3]);
        *(float4*)(outp + (size_t)(m0 + ty * 4 + i) * HS + tx * 4) = r;
    }
}

// ---------------------------------------------------------------------------
// Kernel 2: flash-style causal attention.
// One block = 256 threads = one (batch, 16-query tile). Iterate 64-key tiles
// with online softmax. Row r of the softmax state is owned by wave r>>2, and
// phase C threads read only rows their own wave owns -> no barrier between
// softmax update and PV accumulate.
// ---------------------------------------------------------------------------
constexpr int TQ = 16;   // queries per block
constexpr int TS = 64;   // keys per tile

__launch_bounds__(256) __global__
void attn_kernel(const float* __restrict__ qp,
                 const float* __restrict__ kp,
                 const float* __restrict__ vp,
                 float* __restrict__ out)
{
    const int b  = blockIdx.y;
    const int qt = (int)gridDim.x - 1 - (int)blockIdx.x;  // heavy tiles first
    const int q0 = qt * TQ;
    const int t  = threadIdx.x;

    __shared__ float Qs[TQ][HS + 4];
    __shared__ float Ks[TS][HS + 4];
    __shared__ float Vs[TS][HS + 4];
    __shared__ float Ps[TQ][TS + 4];
    __shared__ float m_s[TQ], l_s[TQ], a_s[TQ];

    {   // load Q tile: 16 rows x 64, one float4 per thread, coalesced
        int qq = t >> 4;
        int hh = (t & 15) * 4;
        *(float4*)&Qs[qq][hh] =
            *(const float4*)(qp + ((size_t)(b * SEQ + q0 + qq) * HS + hh));
    }
    if (t < TQ) { m_s[t] = -INFINITY; l_s[t] = 0.f; }

    const int aq    = t & 15;         // phase A: query row
    const int sg    = t >> 4;         // phase A: key group (4 keys)
    const int myq   = t >> 4;         // phase C: query row (wave w -> rows 4w..4w+3)
    const int myh   = (t & 15) * 4;   // phase C: h base
    const int lane  = t & 63;
    const int wv    = t >> 6;
    const int qglob = q0 + aq;

    float4 o = make_float4(0.f, 0.f, 0.f, 0.f);

    const int nTiles = (q0 + TQ + TS - 1) / TS;
    for (int st = 0; st < nTiles; ++st) {
        // ---- stage K/V tile (fully coalesced float4) ----
        {
            const size_t base = (size_t)(b * SEQ + st * TS) * HS;
#pragma unroll
            for (int r = 0; r < 4; ++r) {
                int f = (r * 256 + t) * 4;       // flat float offset 0..4095
                int s = f >> 6, h = f & 63;
                *(float4*)&Ks[s][h] = *(const float4*)(kp + base + f);
                *(float4*)&Vs[s][h] = *(const float4*)(vp + base + f);
            }
        }
        __syncthreads();

        // ---- phase A: S = Q K^T * scale, causal-masked, into Ps ----
        {
            float a0 = 0.f, a1 = 0.f, a2 = 0.f, a3 = 0.f;
            const int sb = sg * 4;
#pragma unroll
            for (int h4 = 0; h4 < 16; ++h4) {
                float4 qv  = *(float4*)&Qs[aq][h4 * 4];
                float4 k0v = *(float4*)&Ks[sb + 0][h4 * 4];
                float4 k1v = *(float4*)&Ks[sb + 1][h4 * 4];
                float4 k2v = *(float4*)&Ks[sb + 2][h4 * 4];
                float4 k3v = *(float4*)&Ks[sb + 3][h4 * 4];
                a0 += qv.x * k0v.x + qv.y * k0v.y + qv.z * k0v.z + qv.w * k0v.w;
                a1 += qv.x * k1v.x + qv.y * k1v.y + qv.z * k1v.z + qv.w * k1v.w;
                a2 += qv.x * k2v.x + qv.y * k2v.y + qv.z * k2v.z + qv.w * k2v.w;
                a3 += qv.x * k3v.x + qv.y * k3v.y + qv.z * k3v.z + qv.w * k3v.w;
            }
            const int sgl = st * TS + sb;
            Ps[aq][sb + 0] = (sgl + 0 <= qglob) ? a0 * 0.125f : -INFINITY;
            Ps[aq][sb + 1] = (sgl + 1 <= qglob) ? a1 * 0.125f : -INFINITY;
            Ps[aq][sb + 2] = (sgl + 2 <= qglob) ? a2 * 0.125f : -INFINITY;
            Ps[aq][sb + 3] = (sgl + 3 <= qglob) ? a3 * 0.125f : -INFINITY;
        }
        __syncthreads();

        // ---- phase B: online softmax update; wave w owns rows 4w..4w+3 ----
#pragma unroll
        for (int rr = 0; rr < 4; ++rr) {
            const int r = wv * 4 + rr;
            float xv = Ps[r][lane];
            float mx = xv;
#pragma unroll
            for (int off = 32; off > 0; off >>= 1)
                mx = fmaxf(mx, __shfl_xor(mx, off));
            float mold = m_s[r];
            float mnew = fmaxf(mold, mx);
            float p  = __expf(xv - mnew);   // exp(-inf) = 0 handles the mask
            float sm = p;
#pragma unroll
            for (int off = 32; off > 0; off >>= 1)
                sm += __shfl_xor(sm, off);
            Ps[r][lane] = p;
            if (lane == 0) {
                float alpha = __expf(mold - mnew);  // 0 on first valid tile
                a_s[r] = alpha;
                l_s[r] = l_s[r] * alpha + sm;
                m_s[r] = mnew;
            }
        }
        // no barrier: phase C reads only rows this wave wrote in phase B

        // ---- phase C: O = O*alpha + P V ----
        {
            float alpha = a_s[myq];
            o.x *= alpha; o.y *= alpha; o.z *= alpha; o.w *= alpha;
#pragma unroll
            for (int s4 = 0; s4 < 16; ++s4) {
                float4 p4 = *(float4*)&Ps[myq][s4 * 4];
                float4 v0 = *(float4*)&Vs[s4 * 4 + 0][myh];
                float4 v1 = *(float4*)&Vs[s4 * 4 + 1][myh];
                float4 v2 = *(float4*)&Vs[s4 * 4 + 2][myh];
                float4 v3 = *(float4*)&Vs[s4 * 4 + 3][myh];
                o.x += p4.x * v0.x + p4.y * v1.x + p4.z * v2.x + p4.w * v3.x;
                o.y += p4.x * v0.y + p4.y * v1.y + p4.z * v2.y + p4.w * v3.y;
                o.z += p4.x * v0.z + p4.y * v1.z + p4.z * v2.z + p4.w * v3.z;
                o.w += p4.x * v0.w + p4.y * v1.w + p4.z * v2.w + p4.w * v3.w;
            }
        }
        __syncthreads();  // protect Ks/Vs/Ps before next tile's writes
    }

    const float invl = 1.f / l_s[myq];
    float4 r = make_float4(o.x * invl, o.y * invl, o.z * invl, o.w * invl);
    *(float4*)(out + (size_t)(b * SEQ + q0 + myq) * HS + myh) = r;
}

// ---------------------------------------------------------------------------
extern "C" void kernel_launch(void* const* d_in, const int* in_sizes, int n_in,
                              void* d_out, int out_size, void* d_ws, size_t ws_size,
                              hipStream_t stream)
{
    const float* x  = (const float*)d_in[0];
    const float* Wq = (const float*)d_in[1];
    const float* Wk = (const float*)d_in[2];
    const float* Wv = (const float*)d_in[3];
    float* out = (float*)d_out;

    // workspace: q | k | v, each [B*T, H] fp32 (3 * 2 MiB = 6.29 MB)
    float* qkv = (float*)d_ws;

    dim3 g1(BATCH * SEQ / 64, 3);
    qkv_proj_kernel<<<g1, 256, 0, stream>>>(x, Wq, Wk, Wv, qkv);

    const float* q = qkv;
    const float* k = qkv + (size_t)BATCH * SEQ * HS;
    const float* v = qkv + (size_t)2 * BATCH * SEQ * HS;
    dim3 g2(SEQ / TQ, BATCH);
    attn_kernel<<<g2, 256, 0, stream>>>(q, k, v, out);
}

// Round 2
// 161.915 us; speedup vs baseline: 1.9424x; 1.9424x over previous
//
#include <hip/hip_runtime.h>
#include <math.h>

// Problem constants (fixed by the reference).
constexpr int BATCH = 4;
constexpr int SEQ   = 2048;
constexpr int NEMB  = 1024;
constexpr int HS    = 64;

typedef __attribute__((ext_vector_type(8))) short short8;   // MFMA A/B frag (8 bf16)
typedef __attribute__((ext_vector_type(4))) float f32x4;    // MFMA C/D frag

// fp32 -> bf16 bits, round-to-nearest-even
__device__ inline unsigned short f2bf(float f) {
    unsigned u = __builtin_bit_cast(unsigned, f);
    u += 0x7fffu + ((u >> 16) & 1u);
    return (unsigned short)(u >> 16);
}
__device__ inline unsigned long long pack4bf(float a, float b, float c, float d) {
    return (unsigned long long)(f2bf(a) | ((unsigned)f2bf(b) << 16)) |
           ((unsigned long long)(f2bf(c) | ((unsigned)f2bf(d) << 16)) << 32);
}

// ---------------------------------------------------------------------------
// Kernel 1: fused QKV projection, bf16 MFMA 16x16x32.
// C[8192,192] = X[8192,1024] * W[192,1024]^T  (W rows = q|k|v heads).
// BM=64, 512 threads = 8 waves: wave = (mi in 4 m-tiles) x (nh in 2 n-halves
// of 6 n-tiles). A and B both read as row-major [.][k] (the verified B^T
// pattern). Outputs: q,k bf16 row-major [bt][64]; v bf16 TRANSPOSED [b][h][t]
// (C-layout gives each lane 4 consecutive t for fixed h -> one 8B store).
// ---------------------------------------------------------------------------
__launch_bounds__(512) __global__
void qkv_proj(const float* __restrict__ x,  const float* __restrict__ Wq,
              const float* __restrict__ Wk, const float* __restrict__ Wv,
              unsigned short* __restrict__ qb, unsigned short* __restrict__ kb,
              unsigned short* __restrict__ vtb)
{
    __shared__ unsigned short Xs[64][40];    // pad 40: 80B rows, 16B-aligned, 2-way banks
    __shared__ unsigned short Ws[192][40];

    const int m0   = blockIdx.x * 64;
    const int tid  = threadIdx.x;
    const int lane = tid & 63;
    const int wv   = tid >> 6;     // 0..7
    const int mi   = wv & 3;       // m-tile 0..3
    const int nh   = wv >> 2;      // n-half 0..1
    const int quad = lane >> 4;
    const int c    = lane & 15;

    f32x4 acc[6];
#pragma unroll
    for (int j = 0; j < 6; ++j) acc[j] = (f32x4){0.f, 0.f, 0.f, 0.f};

    const int xrow = tid >> 3;        // 0..63
    const int xcol = (tid & 7) * 4;   // 0..28

    for (int k0 = 0; k0 < NEMB; k0 += 32) {
        { // stage X tile 64x32 fp32 -> bf16
            float4 v = *(const float4*)(x + (size_t)(m0 + xrow) * NEMB + k0 + xcol);
            *(unsigned long long*)&Xs[xrow][xcol] = pack4bf(v.x, v.y, v.z, v.w);
        }
#pragma unroll
        for (int p = 0; p < 3; ++p) { // stage W tile 192x32
            int idx4 = p * 512 + tid;          // 0..1535 float4s
            int row  = idx4 >> 3;              // 0..191
            int col  = (idx4 & 7) * 4;
            const float* src = (row < 64) ? (Wq + (size_t)row * NEMB)
                             : (row < 128) ? (Wk + (size_t)(row - 64) * NEMB)
                                           : (Wv + (size_t)(row - 128) * NEMB);
            float4 v = *(const float4*)(src + k0 + col);
            *(unsigned long long*)&Ws[row][col] = pack4bf(v.x, v.y, v.z, v.w);
        }
        __syncthreads();

        // A[m=lane&15][k=quad*8+j] from Xs; B[n=lane&15][k] from Ws (B^T pattern)
        short8 a = *(const short8*)&Xs[mi * 16 + c][quad * 8];
#pragma unroll
        for (int j = 0; j < 6; ++j) {
            short8 bf = *(const short8*)&Ws[(nh * 6 + j) * 16 + c][quad * 8];
            acc[j] = __builtin_amdgcn_mfma_f32_16x16x32_bf16(a, bf, acc[j], 0, 0, 0);
        }
        __syncthreads();
    }

    // Epilogue. C layout: row = quad*4+reg (m), col = lane&15 (n).
    const int mrow = m0 + mi * 16 + quad * 4;   // first of 4 consecutive m rows
#pragma unroll
    for (int j = 0; j < 6; ++j) {
        const int n0 = (nh * 6 + j) * 16;
        const int n  = n0 + c;
        if (n < 128) {          // q or k: row-major [bt][64] bf16
            unsigned short* dst = (n < 64) ? (qb + n) : (kb + (n - 64));
#pragma unroll
            for (int r = 0; r < 4; ++r)
                dst[(size_t)(mrow + r) * HS] = f2bf(acc[j][r]);
        } else {                // v: transposed [b][h][t] bf16, 4 consecutive t
            const int h  = n - 128;
            const int bb = mrow >> 11;
            const int t0 = mrow & 2047;
            *(unsigned long long*)(vtb + ((size_t)bb << 17) + ((size_t)h << 11) + t0) =
                pack4bf(acc[j][0], acc[j][1], acc[j][2], acc[j][3]);
        }
    }
}

// ---------------------------------------------------------------------------
// Kernel 2: MFMA flash attention.
// Block = 256 thr = 4 waves, all sharing ONE 16-query tile; keys split 4-way
// across waves (wave si owns 64-key tiles st == si mod 4), each with private
// online-softmax state (m,l in regs; O in C-layout regs). Block stages 256
// keys/round (K row-major, V pre-transposed). P round-trips through
// wave-private LDS (verified m120 transform). End: cross-wave combine in LDS.
// ---------------------------------------------------------------------------
__launch_bounds__(256) __global__
void attn(const unsigned short* __restrict__ qg, const unsigned short* __restrict__ kg,
          const unsigned short* __restrict__ vtg, float* __restrict__ out)
{
    // Manual carve so the combine buffer can overlap K/V staging.
    __shared__ __align__(16) char smem[80384];
    auto Ks  = (unsigned short(*)[72])smem;              // [256][72] bf16 (36864 B)
    auto Vt  = (unsigned short(*)[264])(smem + 36864);   // [64][264] bf16 (33792 B)
    auto Ps  = (unsigned short(*)[72])(smem + 70656);    // [4*16][72] bf16 (9216 B)
    float* msl = (float*)(smem + 79872);                 // m[4][16] | l[4][16] (512 B)
    auto Oc  = (float(*)[68])smem;                       // [4*16][68] fp32, overlaps Ks

    const int b    = blockIdx.y;
    const int qt   = (int)gridDim.x - 1 - (int)blockIdx.x;  // heavy tiles first
    const int q0   = qt * 16;
    const int tid  = threadIdx.x;
    const int si   = tid >> 6;        // wave = key-split index
    const int lane = tid & 63;
    const int quad = lane >> 4;
    const int c    = lane & 15;

    // Q fragments live in registers for the whole kernel. A[m=c][k=quad*8+j].
    const unsigned short* qrow = qg + (size_t)(b * SEQ + q0 + c) * HS;
    const short8 qa0 = *(const short8*)(qrow + quad * 8);        // h 0..31
    const short8 qa1 = *(const short8*)(qrow + 32 + quad * 8);   // h 32..63

    float m_st[4], l_st[4];
    f32x4 O[4];
#pragma unroll
    for (int r = 0; r < 4; ++r) { m_st[r] = -INFINITY; l_st[r] = 0.f; }
#pragma unroll
    for (int ht = 0; ht < 4; ++ht) O[ht] = (f32x4){0.f, 0.f, 0.f, 0.f};

    const int n_tiles = qt / 4 + 1;            // 64-key tiles needed (causal)
    const int rounds  = (n_tiles + 3) >> 2;

    for (int ro = 0; ro < rounds; ++ro) {
        const int s_base = ro * 256;
        { // stage K: 256 rows x 64 bf16, thread t copies row t (128 B)
            const float4* src = (const float4*)(kg + (size_t)(b * SEQ + s_base + tid) * HS);
            float4* dst = (float4*)&Ks[tid][0];
#pragma unroll
            for (int i = 0; i < 8; ++i) dst[i] = src[i];
        }
        { // stage V^T: 64 rows x 256 bf16; thread t covers (h=t>>2, 64-col chunk)
            const int h = tid >> 2, cp = tid & 3;
            const float4* src = (const float4*)(vtg + ((size_t)b << 17) + ((size_t)h << 11)
                                                + s_base + cp * 64);
            float4* dst = (float4*)&Vt[h][cp * 64];
#pragma unroll
            for (int i = 0; i < 8; ++i) dst[i] = src[i];
        }
        __syncthreads();

        const int st = ro * 4 + si;
        if (st < n_tiles) {
            const bool masked = (st == n_tiles - 1);   // tile containing the diagonal
            // ---- S = Q K^T * scale (C layout: row=q=quad*4+r, col=key=c) ----
            f32x4 sc[4];
#pragma unroll
            for (int nt = 0; nt < 4; ++nt) {
                const int kr = si * 64 + nt * 16 + c;
                short8 kb0 = *(const short8*)&Ks[kr][quad * 8];
                short8 kb1 = *(const short8*)&Ks[kr][32 + quad * 8];
                f32x4 s = (f32x4){0.f, 0.f, 0.f, 0.f};
                s = __builtin_amdgcn_mfma_f32_16x16x32_bf16(qa0, kb0, s, 0, 0, 0);
                s = __builtin_amdgcn_mfma_f32_16x16x32_bf16(qa1, kb1, s, 0, 0, 0);
                sc[nt] = s * 0.125f;
                if (masked) {
                    const int sglob = st * 64 + nt * 16 + c;
#pragma unroll
                    for (int r = 0; r < 4; ++r)
                        if (sglob > q0 + quad * 4 + r) sc[nt][r] = -INFINITY;
                }
            }
            // ---- online softmax per row (reduce across the 16 lanes of a quad) ----
#pragma unroll
            for (int r = 0; r < 4; ++r) {
                float v = fmaxf(fmaxf(sc[0][r], sc[1][r]), fmaxf(sc[2][r], sc[3][r]));
                v = fmaxf(v, __shfl_xor(v, 1));
                v = fmaxf(v, __shfl_xor(v, 2));
                v = fmaxf(v, __shfl_xor(v, 4));
                v = fmaxf(v, __shfl_xor(v, 8));
                const float mnew  = fmaxf(m_st[r], v);
                const float alpha = __expf(m_st[r] - mnew);   // 0 on first tile
                const float p0 = __expf(sc[0][r] - mnew);
                const float p1 = __expf(sc[1][r] - mnew);
                const float p2 = __expf(sc[2][r] - mnew);
                const float p3 = __expf(sc[3][r] - mnew);
                float sum = p0 + p1 + p2 + p3;
                sum += __shfl_xor(sum, 1);
                sum += __shfl_xor(sum, 2);
                sum += __shfl_xor(sum, 4);
                sum += __shfl_xor(sum, 8);
                l_st[r] = l_st[r] * alpha + sum;
                m_st[r] = mnew;
#pragma unroll
                for (int ht = 0; ht < 4; ++ht) O[ht][r] *= alpha;
                const int prow = si * 16 + quad * 4 + r;      // wave-private P buffer
                Ps[prow][c]      = f2bf(p0);
                Ps[prow][16 + c] = f2bf(p1);
                Ps[prow][32 + c] = f2bf(p2);
                Ps[prow][48 + c] = f2bf(p3);
            }
            // ---- O += P V  (A = P from LDS; B = V^T rows, B^T pattern) ----
            short8 pa0 = *(const short8*)&Ps[si * 16 + c][quad * 8];
            short8 pa1 = *(const short8*)&Ps[si * 16 + c][32 + quad * 8];
#pragma unroll
            for (int ht = 0; ht < 4; ++ht) {
                const int vr = ht * 16 + c;
                short8 vb0 = *(const short8*)&Vt[vr][si * 64 + quad * 8];
                short8 vb1 = *(const short8*)&Vt[vr][si * 64 + 32 + quad * 8];
                O[ht] = __builtin_amdgcn_mfma_f32_16x16x32_bf16(pa0, vb0, O[ht], 0, 0, 0);
                O[ht] = __builtin_amdgcn_mfma_f32_16x16x32_bf16(pa1, vb1, O[ht], 0, 0, 0);
            }
        }
        __syncthreads();   // protect Ks/Vt before next round's staging
    }

    // ---- cross-wave combine ----
    if (c == 0) {
#pragma unroll
        for (int r = 0; r < 4; ++r) {
            msl[si * 16 + quad * 4 + r]      = m_st[r];
            msl[64 + si * 16 + quad * 4 + r] = l_st[r];
        }
    }
    __syncthreads();   // msl visible; all Ks/Vt reads drained before Oc overwrite
#pragma unroll
    for (int r = 0; r < 4; ++r) {
        const int row = quad * 4 + r;
        float M = fmaxf(fmaxf(msl[row], msl[16 + row]),
                        fmaxf(msl[32 + row], msl[48 + row]));
        const float scw = __expf(m_st[r] - M);   // 0 for idle waves (m=-inf)
#pragma unroll
        for (int ht = 0; ht < 4; ++ht)
            Oc[si * 16 + row][ht * 16 + c] = O[ht][r] * scw;
    }
    __syncthreads();
    { // final reduce + store: thread -> (row, 4 h)
        const int row = tid >> 4, hb = (tid & 15) * 4;
        float M = fmaxf(fmaxf(msl[row], msl[16 + row]),
                        fmaxf(msl[32 + row], msl[48 + row]));
        float L = 0.f;
#pragma unroll
        for (int w = 0; w < 4; ++w)
            L += __expf(msl[w * 16 + row] - M) * msl[64 + w * 16 + row];
        float ax = 0.f, ay = 0.f, az = 0.f, aw = 0.f;
#pragma unroll
        for (int w = 0; w < 4; ++w) {
            const float4 t = *(const float4*)&Oc[w * 16 + row][hb];
            ax += t.x; ay += t.y; az += t.z; aw += t.w;
        }
        const float inv = 1.f / L;
        *(float4*)(out + (size_t)(b * SEQ + q0 + row) * HS + hb) =
            make_float4(ax * inv, ay * inv, az * inv, aw * inv);
    }
}

// ---------------------------------------------------------------------------
extern "C" void kernel_launch(void* const* d_in, const int* in_sizes, int n_in,
                              void* d_out, int out_size, void* d_ws, size_t ws_size,
                              hipStream_t stream)
{
    const float* x  = (const float*)d_in[0];
    const float* Wq = (const float*)d_in[1];
    const float* Wk = (const float*)d_in[2];
    const float* Wv = (const float*)d_in[3];

    // ws: q bf16 [bt][64] | k bf16 [bt][64] | v^T bf16 [b][h][t]  (3.1 MB)
    unsigned short* qb  = (unsigned short*)d_ws;
    unsigned short* kb  = qb + (size_t)BATCH * SEQ * HS;
    unsigned short* vtb = kb + (size_t)BATCH * SEQ * HS;

    qkv_proj<<<dim3(BATCH * SEQ / 64), dim3(512), 0, stream>>>(x, Wq, Wk, Wv, qb, kb, vtb);
    attn<<<dim3(SEQ / 16, BATCH), dim3(256), 0, stream>>>(qb, kb, vtb, (float*)d_out);
}

// Round 3
// 136.748 us; speedup vs baseline: 2.2998x; 1.1840x over previous
//
#include <hip/hip_runtime.h>
#include <math.h>

// Problem constants (fixed by the reference).
constexpr int BATCH = 4;
constexpr int SEQ   = 2048;
constexpr int NEMB  = 1024;
constexpr int HS    = 64;

typedef __attribute__((ext_vector_type(8))) short short8;   // MFMA A/B frag (8 bf16)
typedef __attribute__((ext_vector_type(4))) float f32x4;    // MFMA C/D frag

// fp32 -> bf16 bits, round-to-nearest-even
__device__ inline unsigned short f2bf(float f) {
    unsigned u = __builtin_bit_cast(unsigned, f);
    u += 0x7fffu + ((u >> 16) & 1u);
    return (unsigned short)(u >> 16);
}
__device__ inline unsigned long long pack4bf(float a, float b, float c, float d) {
    return (unsigned long long)(f2bf(a) | ((unsigned)f2bf(b) << 16)) |
           ((unsigned long long)(f2bf(c) | ((unsigned)f2bf(d) << 16)) << 32);
}

// async 16B global->LDS (direct-to-shared DMA); LDS dest = wave-uniform base + lane*16
__device__ inline void gll16(const void* g, void* l) {
    __builtin_amdgcn_global_load_lds((const __attribute__((address_space(1))) void*)g,
                                     (__attribute__((address_space(3))) void*)l, 16, 0, 0);
}
#define WAIT_VM0()   asm volatile("s_waitcnt vmcnt(0)" ::: "memory")
#define WAIT_LGKM0() asm volatile("s_waitcnt lgkmcnt(0)" ::: "memory")

// ---------------------------------------------------------------------------
// Kernel 0: one-time W fp32 -> bf16 (wbf[192][1024], rows = q|k|v heads).
// ---------------------------------------------------------------------------
__launch_bounds__(256) __global__
void conv_w(const float* __restrict__ Wq, const float* __restrict__ Wk,
            const float* __restrict__ Wv, unsigned short* __restrict__ wbf)
{
    const int idx = (blockIdx.x * 256 + threadIdx.x) * 8;   // 8 floats/thread
    const int row = idx >> 10, col = idx & 1023;
    const float* src = (row < 64) ? (Wq + (size_t)row * NEMB)
                     : (row < 128) ? (Wk + (size_t)(row - 64) * NEMB)
                                   : (Wv + (size_t)(row - 128) * NEMB);
    float4 a = *(const float4*)(src + col);
    float4 b = *(const float4*)(src + col + 4);
    *(unsigned long long*)(wbf + idx)     = pack4bf(a.x, a.y, a.z, a.w);
    *(unsigned long long*)(wbf + idx + 4) = pack4bf(b.x, b.y, b.z, b.w);
}

// ---------------------------------------------------------------------------
// Kernel 1: QKV projection — NO LDS, NO barriers. BM=16, 512 blocks x 4 waves.
// Wave w computes n-tiles {w*48, w*48+16, w*48+32} over C[8192,192].
// A-frags loaded straight from fp32 x (block's 4 waves hit same lines -> L1);
// B-frags straight from bf16 W copy (L2-resident). Waves fully independent.
// ---------------------------------------------------------------------------
__launch_bounds__(256) __global__
void qkv_proj(const float* __restrict__ x, const unsigned short* __restrict__ wbf,
              unsigned short* __restrict__ qb, unsigned short* __restrict__ kb,
              unsigned short* __restrict__ vtb)
{
    const int m0   = blockIdx.x * 16;
    const int tid  = threadIdx.x;
    const int w    = tid >> 6;
    const int lane = tid & 63;
    const int quad = lane >> 4;
    const int c    = lane & 15;

    f32x4 acc[3];
#pragma unroll
    for (int j = 0; j < 3; ++j) acc[j] = (f32x4){0.f, 0.f, 0.f, 0.f};

    const float* xrow = x + (size_t)(m0 + c) * NEMB + quad * 8;
    const unsigned short* wrow = wbf + (size_t)(w * 48 + c) * NEMB + quad * 8;

    union { short8 s8; unsigned long long u[2]; } af;
#pragma unroll 4
    for (int k0 = 0; k0 < NEMB; k0 += 32) {
        float4 a0 = *(const float4*)(xrow + k0);
        float4 a1 = *(const float4*)(xrow + k0 + 4);
        af.u[0] = pack4bf(a0.x, a0.y, a0.z, a0.w);
        af.u[1] = pack4bf(a1.x, a1.y, a1.z, a1.w);
#pragma unroll
        for (int j = 0; j < 3; ++j) {
            short8 bf = *(const short8*)(wrow + (size_t)j * 16 * NEMB + k0);
            acc[j] = __builtin_amdgcn_mfma_f32_16x16x32_bf16(af.s8, bf, acc[j], 0, 0, 0);
        }
    }

    // Epilogue. C layout: row = quad*4+reg (m), col = c (n).
    const int mrow = m0 + quad * 4;
#pragma unroll
    for (int j = 0; j < 3; ++j) {
        const int n = w * 48 + j * 16 + c;
        if (n < 128) {          // q or k: row-major [bt][64] bf16
            unsigned short* dst = (n < 64) ? (qb + n) : (kb + (n - 64));
#pragma unroll
            for (int r = 0; r < 4; ++r)
                dst[(size_t)(mrow + r) * HS] = f2bf(acc[j][r]);
        } else {                // v: transposed [b][h][t] bf16, 4 consecutive t
            const int h  = n - 128;
            const int bb = mrow >> 11;
            const int t0 = mrow & 2047;
            *(unsigned long long*)(vtb + ((size_t)bb << 17) + ((size_t)h << 11) + t0) =
                pack4bf(acc[j][0], acc[j][1], acc[j][2], acc[j][3]);
        }
    }
}

// ---------------------------------------------------------------------------
// Kernel 2: MFMA flash attention, barrier-free K-loop.
// Block = 4 waves sharing one 16-query tile; wave si owns 64-key tiles
// st == si (mod 4) with PRIVATE online-softmax state and a PRIVATE 16 KB
// K/V LDS slice staged via global_load_lds (async DMA). Per-wave
// s_waitcnt vmcnt(0) replaces __syncthreads -> waves never block each other.
// global_load_lds is lane-contiguous (can't pad), so bank conflicts are
// broken by XOR-swizzling the 16B chunk index with (row&7) at stage AND
// read time: bank load is exactly 8 words/bank per b128 (balanced).
// ---------------------------------------------------------------------------
__launch_bounds__(256) __global__
void attn(const unsigned short* __restrict__ qg, const unsigned short* __restrict__ kg,
          const unsigned short* __restrict__ vtg, float* __restrict__ out)
{
    __shared__ __align__(16) char smem[75264];
    // per-wave: K[64][64]bf16 @ si*16384, V[64][64]bf16 @ si*16384+8192 (swizzled)
    auto Ps  = (unsigned short(*)[72])(smem + 65536);   // [64][72] bf16 (9216 B)
    float* msl = (float*)(smem + 74752);                // m[4][16] | l[4][16] (512 B)
    auto Oc  = (float(*)[68])smem;                      // [64][68] fp32, overlaps K/V

    const int b    = blockIdx.y;
    const int qt   = (int)gridDim.x - 1 - (int)blockIdx.x;  // heavy tiles first
    const int q0   = qt * 16;
    const int tid  = threadIdx.x;
    const int si   = tid >> 6;
    const int lane = tid & 63;
    const int quad = lane >> 4;
    const int c    = lane & 15;

    char* kv = smem + si * 16384;
    const unsigned short* Kb = (const unsigned short*)kv;
    const unsigned short* Vb = (const unsigned short*)(kv + 8192);

    // Q fragments in registers for the whole kernel. A[m=c][k=quad*8+j].
    const unsigned short* qrow = qg + (size_t)(b * SEQ + q0 + c) * HS;
    const short8 qa0 = *(const short8*)(qrow + quad * 8);
    const short8 qa1 = *(const short8*)(qrow + 32 + quad * 8);

    float m_st[4], l_st[4];
    f32x4 O[4];
#pragma unroll
    for (int r = 0; r < 4; ++r) { m_st[r] = -INFINITY; l_st[r] = 0.f; }
#pragma unroll
    for (int ht = 0; ht < 4; ++ht) O[ht] = (f32x4){0.f, 0.f, 0.f, 0.f};

    const int n_tiles = qt / 4 + 1;            // total 64-key tiles (causal)

    for (int st = si; st < n_tiles; st += 4) {
        const int key0 = st * 64;
        { // ---- stage K tile [64 keys][64 h] (8 async 1KB loads, swizzled) ----
            const unsigned short* kgb = kg + (size_t)(b * SEQ + key0) * HS;
#pragma unroll
            for (int i = 0; i < 8; ++i) {
                const int f = i * 64 + lane, row = f >> 3, ch = f & 7;
                gll16(kgb + (size_t)row * HS + (ch ^ (row & 7)) * 8, kv + i * 1024);
            }
            // ---- stage V^T tile [64 h][64 t] (8 async 1KB loads, swizzled) ----
            const unsigned short* vgb = vtg + ((size_t)b << 17) + key0;
#pragma unroll
            for (int i = 0; i < 8; ++i) {
                const int f = i * 64 + lane, h = f >> 3, ch = f & 7;
                gll16(vgb + ((size_t)h << 11) + (ch ^ (h & 7)) * 8, kv + 8192 + i * 1024);
            }
        }
        WAIT_VM0();   // per-wave drain; NOT a barrier

        const bool masked = (st == n_tiles - 1);
        // ---- S = Q K^T * scale (C layout: row=q=quad*4+r, col=key=c) ----
        f32x4 sc[4];
#pragma unroll
        for (int nt = 0; nt < 4; ++nt) {
            const int kr = nt * 16 + c;
            short8 kb0 = *(const short8*)(Kb + kr * 64 + ((quad)     ^ (kr & 7)) * 8);
            short8 kb1 = *(const short8*)(Kb + kr * 64 + ((4 + quad) ^ (kr & 7)) * 8);
            f32x4 s = (f32x4){0.f, 0.f, 0.f, 0.f};
            s = __builtin_amdgcn_mfma_f32_16x16x32_bf16(qa0, kb0, s, 0, 0, 0);
            s = __builtin_amdgcn_mfma_f32_16x16x32_bf16(qa1, kb1, s, 0, 0, 0);
            sc[nt] = s * 0.125f;
            if (masked) {
                const int sglob = key0 + kr;
#pragma unroll
                for (int r = 0; r < 4; ++r)
                    if (sglob > q0 + quad * 4 + r) sc[nt][r] = -INFINITY;
            }
        }
        // ---- online softmax per row (reduce across the 16 lanes of a quad) ----
#pragma unroll
        for (int r = 0; r < 4; ++r) {
            float v = fmaxf(fmaxf(sc[0][r], sc[1][r]), fmaxf(sc[2][r], sc[3][r]));
            v = fmaxf(v, __shfl_xor(v, 1));
            v = fmaxf(v, __shfl_xor(v, 2));
            v = fmaxf(v, __shfl_xor(v, 4));
            v = fmaxf(v, __shfl_xor(v, 8));
            const float mnew  = fmaxf(m_st[r], v);
            const float alpha = __expf(m_st[r] - mnew);
            const float p0 = __expf(sc[0][r] - mnew);
            const float p1 = __expf(sc[1][r] - mnew);
            const float p2 = __expf(sc[2][r] - mnew);
            const float p3 = __expf(sc[3][r] - mnew);
            float sum = p0 + p1 + p2 + p3;
            sum += __shfl_xor(sum, 1);
            sum += __shfl_xor(sum, 2);
            sum += __shfl_xor(sum, 4);
            sum += __shfl_xor(sum, 8);
            l_st[r] = l_st[r] * alpha + sum;
            m_st[r] = mnew;
#pragma unroll
            for (int ht = 0; ht < 4; ++ht) O[ht][r] *= alpha;
            const int prow = si * 16 + quad * 4 + r;
            Ps[prow][c]      = f2bf(p0);
            Ps[prow][16 + c] = f2bf(p1);
            Ps[prow][32 + c] = f2bf(p2);
            Ps[prow][48 + c] = f2bf(p3);
        }
        // ---- O += P V (A = P via LDS; B = V^T rows, swizzled chunks) ----
        short8 pa0 = *(const short8*)&Ps[si * 16 + c][quad * 8];
        short8 pa1 = *(const short8*)&Ps[si * 16 + c][32 + quad * 8];
#pragma unroll
        for (int ht = 0; ht < 4; ++ht) {
            const int vr = ht * 16 + c;
            short8 vb0 = *(const short8*)(Vb + vr * 64 + ((quad)     ^ (vr & 7)) * 8);
            short8 vb1 = *(const short8*)(Vb + vr * 64 + ((4 + quad) ^ (vr & 7)) * 8);
            O[ht] = __builtin_amdgcn_mfma_f32_16x16x32_bf16(pa0, vb0, O[ht], 0, 0, 0);
            O[ht] = __builtin_amdgcn_mfma_f32_16x16x32_bf16(pa1, vb1, O[ht], 0, 0, 0);
        }
        WAIT_LGKM0();  // all ds_reads landed before next tile's DMA overwrites
    }

    // ---- cross-wave combine (the only barriers in the kernel) ----
    if (c == 0) {
#pragma unroll
        for (int r = 0; r < 4; ++r) {
            msl[si * 16 + quad * 4 + r]      = m_st[r];
            msl[64 + si * 16 + quad * 4 + r] = l_st[r];
        }
    }
    __syncthreads();
#pragma unroll
    for (int r = 0; r < 4; ++r) {
        const int row = quad * 4 + r;
        float M = fmaxf(fmaxf(msl[row], msl[16 + row]),
                        fmaxf(msl[32 + row], msl[48 + row]));
        const float scw = __expf(m_st[r] - M);   // 0 for idle waves (m=-inf)
#pragma unroll
        for (int ht = 0; ht < 4; ++ht)
            Oc[si * 16 + row][ht * 16 + c] = O[ht][r] * scw;
    }
    __syncthreads();
    {
        const int row = tid >> 4, hb = (tid & 15) * 4;
        float M = fmaxf(fmaxf(msl[row], msl[16 + row]),
                        fmaxf(msl[32 + row], msl[48 + row]));
        float L = 0.f;
#pragma unroll
        for (int w = 0; w < 4; ++w)
            L += __expf(msl[w * 16 + row] - M) * msl[64 + w * 16 + row];
        float ax = 0.f, ay = 0.f, az = 0.f, aw = 0.f;
#pragma unroll
        for (int w = 0; w < 4; ++w) {
            const float4 t = *(const float4*)&Oc[w * 16 + row][hb];
            ax += t.x; ay += t.y; az += t.z; aw += t.w;
        }
        const float inv = 1.f / L;
        *(float4*)(out + (size_t)(b * SEQ + q0 + row) * HS + hb) =
            make_float4(ax * inv, ay * inv, az * inv, aw * inv);
    }
}

// ---------------------------------------------------------------------------
extern "C" void kernel_launch(void* const* d_in, const int* in_sizes, int n_in,
                              void* d_out, int out_size, void* d_ws, size_t ws_size,
                              hipStream_t stream)
{
    const float* x  = (const float*)d_in[0];
    const float* Wq = (const float*)d_in[1];
    const float* Wk = (const float*)d_in[2];
    const float* Wv = (const float*)d_in[3];

    // ws: q bf16 [bt][64] | k bf16 [bt][64] | v^T bf16 [b][h][t] | W bf16 [192][1024]
    unsigned short* qb  = (unsigned short*)d_ws;
    unsigned short* kb  = qb  + (size_t)BATCH * SEQ * HS;
    unsigned short* vtb = kb  + (size_t)BATCH * SEQ * HS;
    unsigned short* wbf = vtb + (size_t)BATCH * SEQ * HS;

    conv_w  <<<dim3(96),                dim3(256), 0, stream>>>(Wq, Wk, Wv, wbf);
    qkv_proj<<<dim3(BATCH * SEQ / 16),  dim3(256), 0, stream>>>(x, wbf, qb, kb, vtb);
    attn    <<<dim3(SEQ / 16, BATCH),   dim3(256), 0, stream>>>(qb, kb, vtb, (float*)d_out);
}